// Round 1
// baseline (1678.830 us; speedup 1.0000x reference)
//
#include <hip/hip_runtime.h>

#define CH 128
#define HH 96
#define WW 96

// ---------------------------------------------------------------------------
// Kernel 1: one-hot grouped conv (16 groups x 8 filters, 3x3 VALID) + bias + relu
// out: (128, 94, 94) CHW
// ---------------------------------------------------------------------------
__global__ __launch_bounds__(256)
void cat_conv_kernel(const int* __restrict__ x,
                     const float* __restrict__ cat_w,
                     const float* __restrict__ cat_b,
                     float* __restrict__ y0) {
    const int HO = 94, WO = 94;
    int idx = blockIdx.x * blockDim.x + threadIdx.x;
    if (idx >= CH * HO * WO) return;
    int w = idx % WO;
    int h = (idx / WO) % HO;
    int c = idx / (WO * HO);
    int g = c >> 3;                    // piece group
    float acc = cat_b[c];
    const float* wp = cat_w + c * 9;   // (16,8,1,3,3) flat == c*9
#pragma unroll
    for (int kh = 0; kh < 3; kh++) {
        const int* xr = x + (h + kh) * WW + w;
#pragma unroll
        for (int kw = 0; kw < 3; kw++) {
            if (xr[kw] == g) acc += wp[kh * 3 + kw];
        }
    }
    y0[idx] = fmaxf(acc, 0.0f);
}

// ---------------------------------------------------------------------------
// Kernel 2: direct 128->128 3x3 VALID conv + bias + relu, CHW layout.
// Block: x = output channel (128), y = 2-row stripe. 128 threads over width.
// Rows-per-block = 2 chosen so HO (92 and 90) divide evenly and input row
// reads (h0..h0+3) never exceed HI for either size -> no guards.
// Weights are block-uniform -> scalar (s_load) broadcasts.
// ---------------------------------------------------------------------------
template<int HI>
__global__ __launch_bounds__(128)
void conv_relu_kernel(const float* __restrict__ in,
                      const float* __restrict__ wgt,
                      const float* __restrict__ bias,
                      float* __restrict__ out) {
    constexpr int WI = HI, HO = HI - 2, WO = WI - 2;
    const int co = blockIdx.x;
    const int h0 = blockIdx.y * 2;
    const int wcol = threadIdx.x;
    if (wcol >= WO) return;
    float b = bias[co];
    float acc0 = b, acc1 = b;
    const float* wbase = wgt + co * (CH * 9);
    const float* ibase = in + h0 * WI + wcol;
    for (int ci = 0; ci < CH; ci++) {
        const float* ib = ibase + ci * (HI * WI);
        const float* wp = wbase + ci * 9;
        float w00 = wp[0], w01 = wp[1], w02 = wp[2];
        float w10 = wp[3], w11 = wp[4], w12 = wp[5];
        float w20 = wp[6], w21 = wp[7], w22 = wp[8];
        float r0a = ib[0],      r0b = ib[1],        r0c = ib[2];
        float r1a = ib[WI],     r1b = ib[WI + 1],   r1c = ib[WI + 2];
        float r2a = ib[2 * WI], r2b = ib[2 * WI + 1], r2c = ib[2 * WI + 2];
        float r3a = ib[3 * WI], r3b = ib[3 * WI + 1], r3c = ib[3 * WI + 2];
        acc0 = fmaf(r0a, w00, acc0); acc0 = fmaf(r0b, w01, acc0); acc0 = fmaf(r0c, w02, acc0);
        acc0 = fmaf(r1a, w10, acc0); acc0 = fmaf(r1b, w11, acc0); acc0 = fmaf(r1c, w12, acc0);
        acc0 = fmaf(r2a, w20, acc0); acc0 = fmaf(r2b, w21, acc0); acc0 = fmaf(r2c, w22, acc0);
        acc1 = fmaf(r1a, w00, acc1); acc1 = fmaf(r1b, w01, acc1); acc1 = fmaf(r1c, w02, acc1);
        acc1 = fmaf(r2a, w10, acc1); acc1 = fmaf(r2b, w11, acc1); acc1 = fmaf(r2c, w12, acc1);
        acc1 = fmaf(r3a, w20, acc1); acc1 = fmaf(r3b, w21, acc1); acc1 = fmaf(r3c, w22, acc1);
    }
    out[(co * HO + h0) * WO + wcol]       = fmaxf(acc0, 0.0f);
    out[(co * HO + h0 + 1) * WO + wcol]   = fmaxf(acc1, 0.0f);
}

// ---------------------------------------------------------------------------
// Kernel 3a: out[i] = lin_b[i]  (256 outputs)
// ---------------------------------------------------------------------------
__global__ void init_out_kernel(const float* __restrict__ lin_b,
                                float* __restrict__ out) {
    out[threadIdx.x] = lin_b[threadIdx.x];
}

// ---------------------------------------------------------------------------
// Kernel 3b: linear layer, 256 x 1,036,800 dot products. HBM-bound on lin_w.
// Each block handles 8 output rows over one 1/128 chunk of the feature dim,
// so the activation float4 stream is reused 8x (stays in L2/L3) and the
// weight stream is a single coalesced pass over 1.06 GB.
// ---------------------------------------------------------------------------
__global__ __launch_bounds__(256)
void linear_kernel(const float* __restrict__ act,
                   const float* __restrict__ lw,
                   float* __restrict__ out) {
    const int NV4 = 259200;   // FEAT / 4
    const int CHUNK = 2025;   // NV4 / 128
    const int og = blockIdx.y;             // output group: rows og*8 .. og*8+7
    const int c0 = blockIdx.x * CHUNK;
    const float4* ap = (const float4*)act;
    const float4* wp = (const float4*)lw + (size_t)(og * 8) * NV4;
    float s[8] = {0.f, 0.f, 0.f, 0.f, 0.f, 0.f, 0.f, 0.f};
    for (int i = c0 + (int)threadIdx.x; i < c0 + CHUNK; i += 256) {
        float4 a = ap[i];
#pragma unroll
        for (int r = 0; r < 8; r++) {
            float4 w = wp[(size_t)r * NV4 + i];
            s[r] = fmaf(a.x, w.x, s[r]);
            s[r] = fmaf(a.y, w.y, s[r]);
            s[r] = fmaf(a.z, w.z, s[r]);
            s[r] = fmaf(a.w, w.w, s[r]);
        }
    }
    __shared__ float red[4][8];
    int lane = threadIdx.x & 63, wv = threadIdx.x >> 6;
#pragma unroll
    for (int r = 0; r < 8; r++) {
        float v = s[r];
        v += __shfl_down(v, 32, 64);
        v += __shfl_down(v, 16, 64);
        v += __shfl_down(v, 8, 64);
        v += __shfl_down(v, 4, 64);
        v += __shfl_down(v, 2, 64);
        v += __shfl_down(v, 1, 64);
        if (lane == 0) red[wv][r] = v;
    }
    __syncthreads();
    if (threadIdx.x < 8) {
        int r = threadIdx.x;
        float t = red[0][r] + red[1][r] + red[2][r] + red[3][r];
        atomicAdd(&out[og * 8 + r], t);
    }
}

// ---------------------------------------------------------------------------
extern "C" void kernel_launch(void* const* d_in, const int* in_sizes, int n_in,
                              void* d_out, int out_size, void* d_ws, size_t ws_size,
                              hipStream_t stream) {
    const int*   x      = (const int*)d_in[0];
    const float* cat_w  = (const float*)d_in[1];
    const float* cat_b  = (const float*)d_in[2];
    const float* conv_w = (const float*)d_in[3];
    const float* conv_b = (const float*)d_in[4];
    const float* lin_w  = (const float*)d_in[5];
    const float* lin_b  = (const float*)d_in[6];
    float* out = (float*)d_out;

    // workspace: bufA = y0 (128*94*94) then reused for y2 (128*90*90);
    //            bufB = y1 (128*92*92)
    float* bufA = (float*)d_ws;
    float* bufB = bufA + 128 * 94 * 94;
    // total ws use: (128*94*94 + 128*92*92) * 4 B  ~= 8.9 MB

    // out = lin_b (d_out is poisoned before every timed launch)
    init_out_kernel<<<1, 256, 0, stream>>>(lin_b, out);

    // y0 = relu(grouped one-hot conv + cat_b): (128, 94, 94)
    {
        int total = CH * 94 * 94;
        cat_conv_kernel<<<(total + 255) / 256, 256, 0, stream>>>(x, cat_w, cat_b, bufA);
    }

    // y1 = relu(conv(y0) + b): (128, 92, 92)
    conv_relu_kernel<94><<<dim3(CH, 46), 128, 0, stream>>>(bufA, conv_w, conv_b, bufB);
    // y2 = relu(conv(y1) + b): (128, 90, 90)   (overwrites bufA; conv2 reads only bufB)
    conv_relu_kernel<92><<<dim3(CH, 45), 128, 0, stream>>>(bufB, conv_w, conv_b, bufA);

    // out += y2 . lin_w^T   (8 outputs/block x 128 feature chunks)
    linear_kernel<<<dim3(128, 32), 256, 0, stream>>>(bufA, lin_w, out);
}